// Round 15
// baseline (111.088 us; speedup 1.0000x reference)
//
#include <hip/hip_runtime.h>

#define NFEAT 256
#define NHID 128
#define NCLASS 32

typedef __attribute__((ext_vector_type(8))) short short8;
typedef __attribute__((ext_vector_type(4))) float f32x4;
typedef __attribute__((ext_vector_type(4))) int int4v;

static __device__ __forceinline__ unsigned short f2bf(float f) {
    unsigned u = __float_as_uint(f);
    unsigned r = (u + 0x7fffu + ((u >> 16) & 1u)) >> 16;   // RNE
    return (unsigned short)r;
}
static __device__ __forceinline__ float bf_lo(unsigned d) {
    return __uint_as_float(d << 16);
}
static __device__ __forceinline__ float bf_hi(unsigned d) {
    return __uint_as_float(d & 0xffff0000u);
}

// ---------------------------------------------------------------- prep:
// blocks 0..127   : precast W1 fp32 [256k][128c] -> W1t bf16 [128c][256k]
// blocks 128..383 : per-CHUNK bucket histogram (vectorized) -> bkt_partial
__global__ __launch_bounds__(256) void prep_kernel(
    const float* __restrict__ W1, unsigned short* __restrict__ W1t,
    const int* __restrict__ dst, int* __restrict__ bkt_partial,
    int E, int CE, int shift)
{
    const int tid = threadIdx.x;
    if (blockIdx.x < 128) {
        int o = blockIdx.x * 256 + tid;
        int c = o >> 8, k = o & 255;
        W1t[o] = f2bf(W1[(size_t)k * NHID + c]);
    } else {
        __shared__ int h[256];
        const int kb = blockIdx.x - 128;
        const int start = kb * CE;           // CE multiple of 4 -> aligned
        const int end = min(start + CE, E);
        h[tid] = 0;
        __syncthreads();
        for (int e4 = start + tid * 4; e4 < end; e4 += 1024) {
            if (e4 + 3 < end) {
                int4 d4 = *(const int4*)&dst[e4];
                atomicAdd(&h[d4.x >> shift], 1);
                atomicAdd(&h[d4.y >> shift], 1);
                atomicAdd(&h[d4.z >> shift], 1);
                atomicAdd(&h[d4.w >> shift], 1);
            } else {
                for (int e = e4; e < end; ++e)
                    atomicAdd(&h[dst[e] >> shift], 1);
            }
        }
        __syncthreads();
        bkt_partial[kb * 256 + tid] = h[tid];
    }
}

// ---------------------------------------------------------------- scan
__global__ __launch_bounds__(256) void scan_kernel(
    const int* __restrict__ bkt_partial, int* __restrict__ chunk_pre,
    int* __restrict__ bkt_base, int E)
{
    __shared__ int s[256];
    const int t = threadIdx.x;
    int run = 0;
    for (int kb = 0; kb < 256; ++kb) {
        chunk_pre[kb * 256 + t] = run;
        run += bkt_partial[kb * 256 + t];
    }
    s[t] = run;
    __syncthreads();
    for (int off = 1; off < 256; off <<= 1) {
        int tv = (t >= off) ? s[t - off] : 0;
        __syncthreads();
        s[t] += tv;
        __syncthreads();
    }
    bkt_base[t] = s[t] - run;
    if (t == 255) bkt_base[256] = s[255];
}

// ---------------------------------------------------------------- GEMM1 + bucket scatter (fused launch)
// blocks 0..255    : bucket scatter (vec4 edge reads, LDS cursor)
// blocks 256..     : gemm1 MFMA 64-row tiles (per-K-tile W staging, 24 KB LDS)
__global__ __launch_bounds__(256) void gemm1_scatter_kernel(
    const float* __restrict__ x, const unsigned short* __restrict__ W1t,
    const float* __restrict__ b1, unsigned short* __restrict__ h1b, int N,
    const int* __restrict__ src, const int* __restrict__ dst,
    const float* __restrict__ w, const int* __restrict__ bkt_base,
    const int* __restrict__ chunk_pre, uint2* __restrict__ bkt_edges,
    int E, int CE, int shift)
{
    __shared__ union SM {
        struct { unsigned short wt[128 * 64]; unsigned short xs[64 * 64]; } g;
        int cur[256];
    } sm;
    const int tid = threadIdx.x;

    if (blockIdx.x < 256) {
        // ---------------- bucket scatter ----------------
        const int kb = blockIdx.x;
        sm.cur[tid] = bkt_base[tid] + chunk_pre[kb * 256 + tid];
        __syncthreads();
        const int start = kb * CE;
        const int end = min(start + CE, E);
        const unsigned lmask = (1u << shift) - 1u;
        for (int e4 = start + tid * 4; e4 < end; e4 += 1024) {
            if (e4 + 3 < end) {
                int4 d4 = *(const int4*)&dst[e4];
                int4 s4 = *(const int4*)&src[e4];
                float4 w4 = *(const float4*)&w[e4];
                int dd[4] = {d4.x, d4.y, d4.z, d4.w};
                int ss[4] = {s4.x, s4.y, s4.z, s4.w};
                float ww[4] = {w4.x, w4.y, w4.z, w4.w};
#pragma unroll
                for (int j = 0; j < 4; ++j) {
                    int b = dd[j] >> shift;
                    int pos = atomicAdd(&sm.cur[b], 1);
                    uint2 rec;
                    rec.x = (unsigned)ss[j] | (((unsigned)dd[j] & lmask) << 24);
                    rec.y = __float_as_uint(ww[j]);
                    bkt_edges[pos] = rec;
                }
            } else {
                for (int e = e4; e < end; ++e) {
                    int d = dst[e];
                    int b = d >> shift;
                    int pos = atomicAdd(&sm.cur[b], 1);
                    uint2 rec;
                    rec.x = (unsigned)src[e] | (((unsigned)d & lmask) << 24);
                    rec.y = __float_as_uint(w[e]);
                    bkt_edges[pos] = rec;
                }
            }
        }
        return;
    }

    // ---------------- gemm1 tile ----------------
    const int lane = tid & 63;
    const int wv = tid >> 6;
    const int row0 = (blockIdx.x - 256) * 64;
    const int l15 = lane & 15;
    const int l47 = lane >> 4;
    const int r7 = lane & 7;

    auto stage_wt = [&](int t) {
#pragma unroll
        for (int j = 0; j < 4; ++j) {
            int si = tid + j * 256;            // 1024 16B slots
            int c = si >> 3, s = si & 7;
            int sp = s ^ (c & 7);
            const int4v* wsrc = (const int4v*)(W1t + (size_t)c * 256 + t * 64);
            int4v v = wsrc[s];
            *(int4v*)&sm.g.wt[c * 64 + sp * 8] = v;
        }
    };
    auto stage_x = [&](int t) {
#pragma unroll
        for (int j = 0; j < 2; ++j) {
            int si = tid + j * 256;
            int r = si >> 3, s = si & 7;
            int row = row0 + r;
            float4 v0 = make_float4(0.f, 0.f, 0.f, 0.f), v1 = v0;
            if (row < N) {
                const float4* xp = (const float4*)&x[(size_t)row * NFEAT + t * 64 + s * 8];
                v0 = xp[0]; v1 = xp[1];
            }
            int w0 = f2bf(v0.x) | ((unsigned)f2bf(v0.y) << 16);
            int w1 = f2bf(v0.z) | ((unsigned)f2bf(v0.w) << 16);
            int w2 = f2bf(v1.x) | ((unsigned)f2bf(v1.y) << 16);
            int w3 = f2bf(v1.z) | ((unsigned)f2bf(v1.w) << 16);
            int sp = s ^ (r & 7);
            int4v pv; pv[0] = w0; pv[1] = w1; pv[2] = w2; pv[3] = w3;
            *(int4v*)&sm.g.xs[r * 64 + sp * 8] = pv;
        }
    };

    f32x4 acc[8];
#pragma unroll
    for (int cf = 0; cf < 8; ++cf)
#pragma unroll
        for (int r = 0; r < 4; ++r) acc[cf][r] = 0.f;

    const int arow = wv * 16 + l15;
#pragma unroll
    for (int t = 0; t < 4; ++t) {
        stage_wt(t);
        stage_x(t);
        __syncthreads();
        short8 af[2];
#pragma unroll
        for (int kf = 0; kf < 2; ++kf) {
            int slot = (kf * 4 + l47) ^ r7;
            af[kf] = *(const short8*)&sm.g.xs[arow * 64 + slot * 8];
        }
#pragma unroll
        for (int cf = 0; cf < 8; ++cf) {
            const int brow = cf * 16 + l15;
#pragma unroll
            for (int kf = 0; kf < 2; ++kf) {
                int slot = (kf * 4 + l47) ^ r7;
                short8 bfr = *(const short8*)&sm.g.wt[brow * 64 + slot * 8];
                acc[cf] = __builtin_amdgcn_mfma_f32_16x16x32_bf16(af[kf], bfr, acc[cf], 0, 0, 0);
            }
        }
        __syncthreads();
    }

#pragma unroll
    for (int cf = 0; cf < 8; ++cf) {
        float bias = b1[cf * 16 + l15];
#pragma unroll
        for (int r = 0; r < 4; ++r) {
            int row = row0 + wv * 16 + l47 * 4 + r;
            if (row < N)
                h1b[(size_t)row * NHID + cf * 16 + l15] = f2bf(acc[cf][r] + bias);
        }
    }
}

// ---------------------------------------------------------------- fine scatter + row_ptr
__global__ __launch_bounds__(1024) void fine_scatter_kernel(
    const int* __restrict__ bkt_base, const uint2* __restrict__ bkt_edges,
    int* __restrict__ row_ptr, uint2* __restrict__ csr_e,
    int shift, int N, int E)
{
    __shared__ int h[256];
    __shared__ int cur[256];
    const int b = blockIdx.x;
    const int t = threadIdx.x;
    const int lo = bkt_base[b], hi = bkt_base[b + 1];
    const int dbase = b << shift;

    if (t < 256) h[t] = 0;
    __syncthreads();
    for (int i = lo + t; i < hi; i += 1024)
        atomicAdd(&h[bkt_edges[i].x >> 24], 1);
    __syncthreads();
    int v = (t < 256) ? h[t] : 0;
    for (int off = 1; off < 256; off <<= 1) {
        int tv = (t >= off && t < 256) ? h[t - off] : 0;
        __syncthreads();
        if (t < 256) h[t] += tv;
        __syncthreads();
    }
    if (t < 256) {
        int excl = h[t] - v;
        int r = dbase + t;
        if (r < N) row_ptr[r] = lo + excl;
        cur[t] = lo + excl;
    }
    if (b == 0 && t == 0) row_ptr[N] = E;
    __syncthreads();
    for (int i = lo + t; i < hi; i += 1024) {
        uint2 rec = bkt_edges[i];
        int dl = rec.x >> 24;
        int pos = atomicAdd(&cur[dl], 1);
        uint2 o;
        o.x = rec.x & 0xFFFFFFu;
        o.y = rec.y;
        csr_e[pos] = o;
    }
}

// ---------------------------------------------------------------- SpMM1 + ReLU + GEMM2
__global__ __launch_bounds__(512) void spmm1_gemm2_kernel(
    const int* __restrict__ row_ptr, const uint2* __restrict__ csr_e,
    const unsigned short* __restrict__ h1b, const float* __restrict__ W2,
    const float* __restrict__ b2, unsigned* __restrict__ h2b, int N)
{
    __shared__ float w2s[NHID * NCLASS];   // 16 KB, [k][c]
    __shared__ float hrow[8][NHID];        // 4 KB
    const int tid = threadIdx.x;
#pragma unroll
    for (int j = 0; j < 8; ++j) {
        int idx = tid + j * 512;
        w2s[idx] = W2[idx];
    }
    __syncthreads();

    const int lane = tid & 63;
    const int wv = tid >> 6;
    const int row = __builtin_amdgcn_readfirstlane(blockIdx.x * 8 + wv);
    if (row >= N) return;

    const int e0 = row_ptr[row], e1 = row_ptr[row + 1];
    const size_t loff = (size_t)(lane * 2);
    float a0 = 0.f, a1 = 0.f;
    int e = e0;
    for (; e + 8 <= e1; e += 8) {
        uint2 r[8];
#pragma unroll
        for (int j = 0; j < 8; ++j) r[j] = csr_e[e + j];
        unsigned d[8];
#pragma unroll
        for (int j = 0; j < 8; ++j)
            d[j] = *(const unsigned*)(h1b + (size_t)r[j].x * NHID + loff);
#pragma unroll
        for (int j = 0; j < 8; ++j) {
            float w = __uint_as_float(r[j].y);
            a0 += w * bf_lo(d[j]); a1 += w * bf_hi(d[j]);
        }
    }
    if (e + 4 <= e1) {
        uint2 r[4];
#pragma unroll
        for (int j = 0; j < 4; ++j) r[j] = csr_e[e + j];
        unsigned d[4];
#pragma unroll
        for (int j = 0; j < 4; ++j)
            d[j] = *(const unsigned*)(h1b + (size_t)r[j].x * NHID + loff);
#pragma unroll
        for (int j = 0; j < 4; ++j) {
            float w = __uint_as_float(r[j].y);
            a0 += w * bf_lo(d[j]); a1 += w * bf_hi(d[j]);
        }
        e += 4;
    }
    if (e + 2 <= e1) {
        uint2 r0 = csr_e[e], r1 = csr_e[e + 1];
        unsigned d0 = *(const unsigned*)(h1b + (size_t)r0.x * NHID + loff);
        unsigned d1 = *(const unsigned*)(h1b + (size_t)r1.x * NHID + loff);
        float w0 = __uint_as_float(r0.y), w1 = __uint_as_float(r1.y);
        a0 += w0 * bf_lo(d0); a1 += w0 * bf_hi(d0);
        a0 += w1 * bf_lo(d1); a1 += w1 * bf_hi(d1);
        e += 2;
    }
    if (e < e1) {
        uint2 r = csr_e[e];
        float w = __uint_as_float(r.y);
        unsigned d = *(const unsigned*)(h1b + (size_t)r.x * NHID + loff);
        a0 += w * bf_lo(d); a1 += w * bf_hi(d);
    }
    *(float2*)&hrow[wv][lane * 2] = make_float2(fmaxf(a0, 0.f), fmaxf(a1, 0.f));

    const int c = lane & 31;
    const int kh = lane >> 5;
    const float* hw = &hrow[wv][kh * 64];
    const float* wp = &w2s[(size_t)kh * 64 * NCLASS + c];
    float acc = 0.f;
#pragma unroll
    for (int k = 0; k < 64; ++k)
        acc += hw[k] * wp[k * NCLASS];
    acc += __shfl(acc, lane ^ 32);
    float accb = acc + b2[c];
    float nb = __shfl(accb, lane ^ 1);
    if (kh == 0 && (lane & 1) == 0) {
        unsigned u = (unsigned)f2bf(accb) | ((unsigned)f2bf(nb) << 16);
        h2b[(size_t)row * 16 + (lane >> 1)] = u;
    }
}

// ---------------------------------------------------------------- SpMM2 (unroll 16)
__global__ __launch_bounds__(256) void spmm2_kernel(
    const int* __restrict__ row_ptr, const uint2* __restrict__ csr_e,
    const unsigned* __restrict__ h2b, float* __restrict__ out, int N)
{
    const int li = threadIdx.x & 15;
    const int g = threadIdx.x >> 4;
    const int row = blockIdx.x * 16 + g;
    if (row >= N) return;
    const int e0 = row_ptr[row], e1 = row_ptr[row + 1];
    float a0 = 0.f, a1 = 0.f;
    int e = e0;
    for (; e + 16 <= e1; e += 16) {
        uint2 r[16];
#pragma unroll
        for (int j = 0; j < 16; ++j) r[j] = csr_e[e + j];
        unsigned d[16];
#pragma unroll
        for (int j = 0; j < 16; ++j) d[j] = h2b[(size_t)r[j].x * 16 + li];
#pragma unroll
        for (int j = 0; j < 16; ++j) {
            float w = __uint_as_float(r[j].y);
            a0 += w * bf_lo(d[j]); a1 += w * bf_hi(d[j]);
        }
    }
    for (; e + 8 <= e1; e += 8) {
        uint2 r[8];
#pragma unroll
        for (int j = 0; j < 8; ++j) r[j] = csr_e[e + j];
        unsigned d[8];
#pragma unroll
        for (int j = 0; j < 8; ++j) d[j] = h2b[(size_t)r[j].x * 16 + li];
#pragma unroll
        for (int j = 0; j < 8; ++j) {
            float w = __uint_as_float(r[j].y);
            a0 += w * bf_lo(d[j]); a1 += w * bf_hi(d[j]);
        }
    }
    for (; e + 2 <= e1; e += 2) {
        uint2 r0 = csr_e[e], r1 = csr_e[e + 1];
        unsigned d0 = h2b[(size_t)r0.x * 16 + li];
        unsigned d1 = h2b[(size_t)r1.x * 16 + li];
        float w0 = __uint_as_float(r0.y), w1 = __uint_as_float(r1.y);
        a0 += w0 * bf_lo(d0); a1 += w0 * bf_hi(d0);
        a0 += w1 * bf_lo(d1); a1 += w1 * bf_hi(d1);
    }
    if (e < e1) {
        uint2 r = csr_e[e];
        float w = __uint_as_float(r.y);
        unsigned d = h2b[(size_t)r.x * 16 + li];
        a0 += w * bf_lo(d); a1 += w * bf_hi(d);
    }
    *(float2*)&out[(size_t)row * NCLASS + li * 2] = make_float2(a0, a1);
}

// ---------------------------------------------------------------- launch

extern "C" void kernel_launch(void* const* d_in, const int* in_sizes, int n_in,
                              void* d_out, int out_size, void* d_ws, size_t ws_size,
                              hipStream_t stream) {
    const float* x    = (const float*)d_in[0];
    const int*   esrc = (const int*)d_in[1];
    const int*   edst = (const int*)d_in[2];
    const float* ew   = (const float*)d_in[3];
    const float* W1   = (const float*)d_in[4];
    const float* b1   = (const float*)d_in[5];
    const float* W2   = (const float*)d_in[6];
    const float* b2   = (const float*)d_in[7];
    float* out = (float*)d_out;

    const int N = in_sizes[0] / NFEAT;
    const int E = in_sizes[1];

    int shift = 0;
    while (((N - 1) >> shift) >= 256) ++shift;
    const int NBKT = ((N - 1) >> shift) + 1;
    const int CE = (((E + 255) / 256) + 3) & ~3;   // edges/chunk, multiple of 4
    const int ntiles = (N + 63) / 64;

    char* base = (char*)d_ws;
    size_t off = 0;
    auto take = [&](size_t bytes) -> void* {
        void* p = base + off;
        off += (bytes + 255) & ~(size_t)255;
        return p;
    };
    unsigned short* h1b = (unsigned short*)take((size_t)N * NHID * sizeof(unsigned short));
    unsigned* h2b  = (unsigned*)take((size_t)N * 16 * sizeof(unsigned));
    int*   row_ptr = (int*)take((size_t)(N + 1) * sizeof(int));
    int*   bkt_partial = (int*)take(256 * 256 * sizeof(int));
    int*   chunk_pre   = (int*)take(256 * 256 * sizeof(int));
    int*   bkt_base    = (int*)take(257 * sizeof(int));
    uint2* bkt_edges   = (uint2*)take((size_t)E * sizeof(uint2));
    uint2* csr_e       = (uint2*)take((size_t)E * sizeof(uint2));
    unsigned short* W1t = (unsigned short*)take((size_t)NFEAT * NHID * sizeof(unsigned short));
    (void)ws_size; (void)n_in; (void)out_size;

    prep_kernel<<<384, 256, 0, stream>>>(W1, W1t, edst, bkt_partial, E, CE, shift);
    scan_kernel<<<1, 256, 0, stream>>>(bkt_partial, chunk_pre, bkt_base, E);
    gemm1_scatter_kernel<<<256 + ntiles, 256, 0, stream>>>(
        x, W1t, b1, h1b, N, esrc, edst, ew, bkt_base, chunk_pre, bkt_edges, E, CE, shift);
    fine_scatter_kernel<<<NBKT, 1024, 0, stream>>>(bkt_base, bkt_edges, row_ptr, csr_e,
                                                   shift, N, E);
    spmm1_gemm2_kernel<<<(N + 7) / 8, 512, 0, stream>>>(row_ptr, csr_e, h1b, W2, b2, h2b, N);
    spmm2_kernel<<<(N + 15) / 16, 256, 0, stream>>>(row_ptr, csr_e, h2b, out, N);
}

// Round 16
// 102.121 us; speedup vs baseline: 1.0878x; 1.0878x over previous
//
#include <hip/hip_runtime.h>

#define NFEAT 256
#define NHID 128
#define NCLASS 32

typedef __attribute__((ext_vector_type(8))) short short8;
typedef __attribute__((ext_vector_type(4))) float f32x4;
typedef __attribute__((ext_vector_type(4))) int int4v;

static __device__ __forceinline__ unsigned short f2bf(float f) {
    unsigned u = __float_as_uint(f);
    unsigned r = (u + 0x7fffu + ((u >> 16) & 1u)) >> 16;   // RNE
    return (unsigned short)r;
}
static __device__ __forceinline__ float bf_lo(unsigned d) {
    return __uint_as_float(d << 16);
}
static __device__ __forceinline__ float bf_hi(unsigned d) {
    return __uint_as_float(d & 0xffff0000u);
}

// ---------------------------------------------------------------- prep:
// blocks 0..127   : precast W1 fp32 [256k][128c] -> W1t bf16 [128c][256k]
// blocks 128..383 : per-CHUNK bucket histogram (vectorized) -> bkt_partial
__global__ __launch_bounds__(256) void prep_kernel(
    const float* __restrict__ W1, unsigned short* __restrict__ W1t,
    const int* __restrict__ dst, int* __restrict__ bkt_partial,
    int E, int CE, int shift)
{
    const int tid = threadIdx.x;
    if (blockIdx.x < 128) {
        int o = blockIdx.x * 256 + tid;
        int c = o >> 8, k = o & 255;
        W1t[o] = f2bf(W1[(size_t)k * NHID + c]);
    } else {
        __shared__ int h[256];
        const int kb = blockIdx.x - 128;
        const int start = kb * CE;           // CE multiple of 4 -> aligned
        const int end = min(start + CE, E);
        h[tid] = 0;
        __syncthreads();
        for (int e4 = start + tid * 4; e4 < end; e4 += 1024) {
            if (e4 + 3 < end) {
                int4 d4 = *(const int4*)&dst[e4];
                atomicAdd(&h[d4.x >> shift], 1);
                atomicAdd(&h[d4.y >> shift], 1);
                atomicAdd(&h[d4.z >> shift], 1);
                atomicAdd(&h[d4.w >> shift], 1);
            } else {
                for (int e = e4; e < end; ++e)
                    atomicAdd(&h[dst[e] >> shift], 1);
            }
        }
        __syncthreads();
        bkt_partial[kb * 256 + tid] = h[tid];
    }
}

// ---------------------------------------------------------------- scan
__global__ __launch_bounds__(256) void scan_kernel(
    const int* __restrict__ bkt_partial, int* __restrict__ chunk_pre,
    int* __restrict__ bkt_base, int E)
{
    __shared__ int s[256];
    const int t = threadIdx.x;
    int run = 0;
    for (int kb = 0; kb < 256; ++kb) {
        chunk_pre[kb * 256 + t] = run;
        run += bkt_partial[kb * 256 + t];
    }
    s[t] = run;
    __syncthreads();
    for (int off = 1; off < 256; off <<= 1) {
        int tv = (t >= off) ? s[t - off] : 0;
        __syncthreads();
        s[t] += tv;
        __syncthreads();
    }
    bkt_base[t] = s[t] - run;
    if (t == 255) bkt_base[256] = s[255];
}

// ---------------------------------------------------------------- bucket scatter (vec4)
__global__ __launch_bounds__(256) void bucket_scatter_kernel(
    const int* __restrict__ src, const int* __restrict__ dst,
    const float* __restrict__ w, const int* __restrict__ bkt_base,
    const int* __restrict__ chunk_pre, uint2* __restrict__ bkt_edges,
    int E, int CE, int shift)
{
    __shared__ int cur[256];
    const int tid = threadIdx.x;
    const int kb = blockIdx.x;
    cur[tid] = bkt_base[tid] + chunk_pre[kb * 256 + tid];
    __syncthreads();
    const int start = kb * CE;
    const int end = min(start + CE, E);
    const unsigned lmask = (1u << shift) - 1u;
    for (int e4 = start + tid * 4; e4 < end; e4 += 1024) {
        if (e4 + 3 < end) {
            int4 d4 = *(const int4*)&dst[e4];
            int4 s4 = *(const int4*)&src[e4];
            float4 w4 = *(const float4*)&w[e4];
            int dd[4] = {d4.x, d4.y, d4.z, d4.w};
            int ss[4] = {s4.x, s4.y, s4.z, s4.w};
            float ww[4] = {w4.x, w4.y, w4.z, w4.w};
#pragma unroll
            for (int j = 0; j < 4; ++j) {
                int b = dd[j] >> shift;
                int pos = atomicAdd(&cur[b], 1);
                uint2 rec;
                rec.x = (unsigned)ss[j] | (((unsigned)dd[j] & lmask) << 24);
                rec.y = __float_as_uint(ww[j]);
                bkt_edges[pos] = rec;
            }
        } else {
            for (int e = e4; e < end; ++e) {
                int d = dst[e];
                int b = d >> shift;
                int pos = atomicAdd(&cur[b], 1);
                uint2 rec;
                rec.x = (unsigned)src[e] | (((unsigned)d & lmask) << 24);
                rec.y = __float_as_uint(w[e]);
                bkt_edges[pos] = rec;
            }
        }
    }
}

// ---------------------------------------------------------------- fine scatter + row_ptr
__global__ __launch_bounds__(1024) void fine_scatter_kernel(
    const int* __restrict__ bkt_base, const uint2* __restrict__ bkt_edges,
    int* __restrict__ row_ptr, uint2* __restrict__ csr_e,
    int shift, int N, int E)
{
    __shared__ int h[256];
    __shared__ int cur[256];
    const int b = blockIdx.x;
    const int t = threadIdx.x;
    const int lo = bkt_base[b], hi = bkt_base[b + 1];
    const int dbase = b << shift;

    if (t < 256) h[t] = 0;
    __syncthreads();
    for (int i = lo + t; i < hi; i += 1024)
        atomicAdd(&h[bkt_edges[i].x >> 24], 1);
    __syncthreads();
    int v = (t < 256) ? h[t] : 0;
    for (int off = 1; off < 256; off <<= 1) {
        int tv = (t >= off && t < 256) ? h[t - off] : 0;
        __syncthreads();
        if (t < 256) h[t] += tv;
        __syncthreads();
    }
    if (t < 256) {
        int excl = h[t] - v;
        int r = dbase + t;
        if (r < N) row_ptr[r] = lo + excl;
        cur[t] = lo + excl;
    }
    if (b == 0 && t == 0) row_ptr[N] = E;
    __syncthreads();
    for (int i = lo + t; i < hi; i += 1024) {
        uint2 rec = bkt_edges[i];
        int dl = rec.x >> 24;
        int pos = atomicAdd(&cur[dl], 1);
        uint2 o;
        o.x = rec.x & 0xFFFFFFu;
        o.y = rec.y;
        csr_e[pos] = o;
    }
}

// ---------------------------------------------------------------- GEMM1 (MFMA bf16, per-K-tile staging)
// LDS 24 KB -> 6 blocks/CU.
__global__ __launch_bounds__(256) void gemm1_mfma_kernel(
    const float* __restrict__ x, const unsigned short* __restrict__ W1t,
    const float* __restrict__ b1, unsigned short* __restrict__ h1b, int N)
{
    __shared__ unsigned short wt[128 * 64];    // 16 KB: [c][k-tile], swizzled
    __shared__ unsigned short xs[64 * 64];     // 8 KB:  [r][k-tile], swizzled

    const int tid = threadIdx.x;
    const int lane = tid & 63;
    const int wv = tid >> 6;
    const int row0 = blockIdx.x * 64;
    const int l15 = lane & 15;
    const int l47 = lane >> 4;
    const int r7 = lane & 7;

    auto stage_wt = [&](int t) {
#pragma unroll
        for (int j = 0; j < 4; ++j) {
            int si = tid + j * 256;            // 1024 16B slots
            int c = si >> 3, s = si & 7;
            int sp = s ^ (c & 7);
            const int4v* wsrc = (const int4v*)(W1t + (size_t)c * 256 + t * 64);
            int4v v = wsrc[s];
            *(int4v*)&wt[c * 64 + sp * 8] = v;
        }
    };
    auto stage_x = [&](int t) {
#pragma unroll
        for (int j = 0; j < 2; ++j) {
            int si = tid + j * 256;
            int r = si >> 3, s = si & 7;
            int row = row0 + r;
            float4 v0 = make_float4(0.f, 0.f, 0.f, 0.f), v1 = v0;
            if (row < N) {
                const float4* xp = (const float4*)&x[(size_t)row * NFEAT + t * 64 + s * 8];
                v0 = xp[0]; v1 = xp[1];
            }
            int w0 = f2bf(v0.x) | ((unsigned)f2bf(v0.y) << 16);
            int w1 = f2bf(v0.z) | ((unsigned)f2bf(v0.w) << 16);
            int w2 = f2bf(v1.x) | ((unsigned)f2bf(v1.y) << 16);
            int w3 = f2bf(v1.z) | ((unsigned)f2bf(v1.w) << 16);
            int sp = s ^ (r & 7);
            int4v pv; pv[0] = w0; pv[1] = w1; pv[2] = w2; pv[3] = w3;
            *(int4v*)&xs[r * 64 + sp * 8] = pv;
        }
    };

    f32x4 acc[8];
#pragma unroll
    for (int cf = 0; cf < 8; ++cf)
#pragma unroll
        for (int r = 0; r < 4; ++r) acc[cf][r] = 0.f;

    const int arow = wv * 16 + l15;
#pragma unroll
    for (int t = 0; t < 4; ++t) {
        stage_wt(t);
        stage_x(t);
        __syncthreads();
        short8 af[2];
#pragma unroll
        for (int kf = 0; kf < 2; ++kf) {
            int slot = (kf * 4 + l47) ^ r7;
            af[kf] = *(const short8*)&xs[arow * 64 + slot * 8];
        }
#pragma unroll
        for (int cf = 0; cf < 8; ++cf) {
            const int brow = cf * 16 + l15;
#pragma unroll
            for (int kf = 0; kf < 2; ++kf) {
                int slot = (kf * 4 + l47) ^ r7;
                short8 bfr = *(const short8*)&wt[brow * 64 + slot * 8];
                acc[cf] = __builtin_amdgcn_mfma_f32_16x16x32_bf16(af[kf], bfr, acc[cf], 0, 0, 0);
            }
        }
        __syncthreads();
    }

#pragma unroll
    for (int cf = 0; cf < 8; ++cf) {
        float bias = b1[cf * 16 + l15];
#pragma unroll
        for (int r = 0; r < 4; ++r) {
            int row = row0 + wv * 16 + l47 * 4 + r;
            if (row < N)
                h1b[(size_t)row * NHID + cf * 16 + l15] = f2bf(acc[cf][r] + bias);
        }
    }
}

// ---------------------------------------------------------------- SpMM1 + ReLU + GEMM2
__global__ __launch_bounds__(512) void spmm1_gemm2_kernel(
    const int* __restrict__ row_ptr, const uint2* __restrict__ csr_e,
    const unsigned short* __restrict__ h1b, const float* __restrict__ W2,
    const float* __restrict__ b2, unsigned* __restrict__ h2b, int N)
{
    __shared__ float w2s[NHID * NCLASS];   // 16 KB, [k][c]
    __shared__ float hrow[8][NHID];        // 4 KB
    const int tid = threadIdx.x;
#pragma unroll
    for (int j = 0; j < 8; ++j) {
        int idx = tid + j * 512;
        w2s[idx] = W2[idx];
    }
    __syncthreads();

    const int lane = tid & 63;
    const int wv = tid >> 6;
    const int row = __builtin_amdgcn_readfirstlane(blockIdx.x * 8 + wv);
    if (row >= N) return;

    const int e0 = row_ptr[row], e1 = row_ptr[row + 1];
    const size_t loff = (size_t)(lane * 2);
    float a0 = 0.f, a1 = 0.f;
    int e = e0;
    for (; e + 8 <= e1; e += 8) {
        uint2 r[8];
#pragma unroll
        for (int j = 0; j < 8; ++j) r[j] = csr_e[e + j];
        unsigned d[8];
#pragma unroll
        for (int j = 0; j < 8; ++j)
            d[j] = *(const unsigned*)(h1b + (size_t)r[j].x * NHID + loff);
#pragma unroll
        for (int j = 0; j < 8; ++j) {
            float w = __uint_as_float(r[j].y);
            a0 += w * bf_lo(d[j]); a1 += w * bf_hi(d[j]);
        }
    }
    if (e + 4 <= e1) {
        uint2 r[4];
#pragma unroll
        for (int j = 0; j < 4; ++j) r[j] = csr_e[e + j];
        unsigned d[4];
#pragma unroll
        for (int j = 0; j < 4; ++j)
            d[j] = *(const unsigned*)(h1b + (size_t)r[j].x * NHID + loff);
#pragma unroll
        for (int j = 0; j < 4; ++j) {
            float w = __uint_as_float(r[j].y);
            a0 += w * bf_lo(d[j]); a1 += w * bf_hi(d[j]);
        }
        e += 4;
    }
    if (e + 2 <= e1) {
        uint2 r0 = csr_e[e], r1 = csr_e[e + 1];
        unsigned d0 = *(const unsigned*)(h1b + (size_t)r0.x * NHID + loff);
        unsigned d1 = *(const unsigned*)(h1b + (size_t)r1.x * NHID + loff);
        float w0 = __uint_as_float(r0.y), w1 = __uint_as_float(r1.y);
        a0 += w0 * bf_lo(d0); a1 += w0 * bf_hi(d0);
        a0 += w1 * bf_lo(d1); a1 += w1 * bf_hi(d1);
        e += 2;
    }
    if (e < e1) {
        uint2 r = csr_e[e];
        float w = __uint_as_float(r.y);
        unsigned d = *(const unsigned*)(h1b + (size_t)r.x * NHID + loff);
        a0 += w * bf_lo(d); a1 += w * bf_hi(d);
    }
    *(float2*)&hrow[wv][lane * 2] = make_float2(fmaxf(a0, 0.f), fmaxf(a1, 0.f));

    const int c = lane & 31;
    const int kh = lane >> 5;
    const float* hw = &hrow[wv][kh * 64];
    const float* wp = &w2s[(size_t)kh * 64 * NCLASS + c];
    float acc = 0.f;
#pragma unroll
    for (int k = 0; k < 64; ++k)
        acc += hw[k] * wp[k * NCLASS];
    acc += __shfl(acc, lane ^ 32);
    float accb = acc + b2[c];
    float nb = __shfl(accb, lane ^ 1);
    if (kh == 0 && (lane & 1) == 0) {
        unsigned u = (unsigned)f2bf(accb) | ((unsigned)f2bf(nb) << 16);
        h2b[(size_t)row * 16 + (lane >> 1)] = u;
    }
}

// ---------------------------------------------------------------- SpMM2 (unroll 16)
__global__ __launch_bounds__(256) void spmm2_kernel(
    const int* __restrict__ row_ptr, const uint2* __restrict__ csr_e,
    const unsigned* __restrict__ h2b, float* __restrict__ out, int N)
{
    const int li = threadIdx.x & 15;
    const int g = threadIdx.x >> 4;
    const int row = blockIdx.x * 16 + g;
    if (row >= N) return;
    const int e0 = row_ptr[row], e1 = row_ptr[row + 1];
    float a0 = 0.f, a1 = 0.f;
    int e = e0;
    for (; e + 16 <= e1; e += 16) {
        uint2 r[16];
#pragma unroll
        for (int j = 0; j < 16; ++j) r[j] = csr_e[e + j];
        unsigned d[16];
#pragma unroll
        for (int j = 0; j < 16; ++j) d[j] = h2b[(size_t)r[j].x * 16 + li];
#pragma unroll
        for (int j = 0; j < 16; ++j) {
            float w = __uint_as_float(r[j].y);
            a0 += w * bf_lo(d[j]); a1 += w * bf_hi(d[j]);
        }
    }
    for (; e + 8 <= e1; e += 8) {
        uint2 r[8];
#pragma unroll
        for (int j = 0; j < 8; ++j) r[j] = csr_e[e + j];
        unsigned d[8];
#pragma unroll
        for (int j = 0; j < 8; ++j) d[j] = h2b[(size_t)r[j].x * 16 + li];
#pragma unroll
        for (int j = 0; j < 8; ++j) {
            float w = __uint_as_float(r[j].y);
            a0 += w * bf_lo(d[j]); a1 += w * bf_hi(d[j]);
        }
    }
    for (; e + 2 <= e1; e += 2) {
        uint2 r0 = csr_e[e], r1 = csr_e[e + 1];
        unsigned d0 = h2b[(size_t)r0.x * 16 + li];
        unsigned d1 = h2b[(size_t)r1.x * 16 + li];
        float w0 = __uint_as_float(r0.y), w1 = __uint_as_float(r1.y);
        a0 += w0 * bf_lo(d0); a1 += w0 * bf_hi(d0);
        a0 += w1 * bf_lo(d1); a1 += w1 * bf_hi(d1);
    }
    if (e < e1) {
        uint2 r = csr_e[e];
        float w = __uint_as_float(r.y);
        unsigned d = h2b[(size_t)r.x * 16 + li];
        a0 += w * bf_lo(d); a1 += w * bf_hi(d);
    }
    *(float2*)&out[(size_t)row * NCLASS + li * 2] = make_float2(a0, a1);
}

// ---------------------------------------------------------------- launch

extern "C" void kernel_launch(void* const* d_in, const int* in_sizes, int n_in,
                              void* d_out, int out_size, void* d_ws, size_t ws_size,
                              hipStream_t stream) {
    const float* x    = (const float*)d_in[0];
    const int*   esrc = (const int*)d_in[1];
    const int*   edst = (const int*)d_in[2];
    const float* ew   = (const float*)d_in[3];
    const float* W1   = (const float*)d_in[4];
    const float* b1   = (const float*)d_in[5];
    const float* W2   = (const float*)d_in[6];
    const float* b2   = (const float*)d_in[7];
    float* out = (float*)d_out;

    const int N = in_sizes[0] / NFEAT;
    const int E = in_sizes[1];

    int shift = 0;
    while (((N - 1) >> shift) >= 256) ++shift;
    const int NBKT = ((N - 1) >> shift) + 1;
    const int CE = (((E + 255) / 256) + 3) & ~3;   // edges/chunk, multiple of 4

    char* base = (char*)d_ws;
    size_t off = 0;
    auto take = [&](size_t bytes) -> void* {
        void* p = base + off;
        off += (bytes + 255) & ~(size_t)255;
        return p;
    };
    unsigned short* h1b = (unsigned short*)take((size_t)N * NHID * sizeof(unsigned short));
    unsigned* h2b  = (unsigned*)take((size_t)N * 16 * sizeof(unsigned));
    int*   row_ptr = (int*)take((size_t)(N + 1) * sizeof(int));
    int*   bkt_partial = (int*)take(256 * 256 * sizeof(int));
    int*   chunk_pre   = (int*)take(256 * 256 * sizeof(int));
    int*   bkt_base    = (int*)take(257 * sizeof(int));
    uint2* bkt_edges   = (uint2*)take((size_t)E * sizeof(uint2));
    uint2* csr_e       = (uint2*)take((size_t)E * sizeof(uint2));
    unsigned short* W1t = (unsigned short*)take((size_t)NFEAT * NHID * sizeof(unsigned short));
    (void)ws_size; (void)n_in; (void)out_size;

    prep_kernel<<<384, 256, 0, stream>>>(W1, W1t, edst, bkt_partial, E, CE, shift);
    scan_kernel<<<1, 256, 0, stream>>>(bkt_partial, chunk_pre, bkt_base, E);
    bucket_scatter_kernel<<<256, 256, 0, stream>>>(esrc, edst, ew, bkt_base, chunk_pre,
                                                   bkt_edges, E, CE, shift);
    fine_scatter_kernel<<<NBKT, 1024, 0, stream>>>(bkt_base, bkt_edges, row_ptr, csr_e,
                                                   shift, N, E);
    gemm1_mfma_kernel<<<(N + 63) / 64, 256, 0, stream>>>(x, W1t, b1, h1b, N);
    spmm1_gemm2_kernel<<<(N + 7) / 8, 512, 0, stream>>>(row_ptr, csr_e, h1b, W2, b2, h2b, N);
    spmm2_kernel<<<(N + 15) / 16, 256, 0, stream>>>(row_ptr, csr_e, h2b, out, N);
}